// Round 1
// baseline (172.192 us; speedup 1.0000x reference)
//
#include <hip/hip_runtime.h>

#define NUM_PRIORS 65536
#define BATCH 8
#define GNUM 64
#define NBLK 256

// ---------------------------------------------------------------------------
// Kernel 1: per (b, g), find argmax over all priors of IoU(prior, gt[b][g]).
// One block per (b,g); 256 threads grid-stride over P; tree-reduce with
// first-occurrence (smallest index) tie-break to match jnp.argmax semantics.
// ---------------------------------------------------------------------------
__global__ __launch_bounds__(NBLK) void best_prior_kernel(
    const float* __restrict__ priors,    // [P,4] corner
    const float* __restrict__ gt_boxes,  // [B,G,4] corner
    int* __restrict__ bpi)               // [B,G] out
{
    const int b = blockIdx.x / GNUM;
    const int g = blockIdx.x % GNUM;

    const float4 gb = *reinterpret_cast<const float4*>(gt_boxes + (b * GNUM + g) * 4);
    const float area_g = (gb.z - gb.x) * (gb.w - gb.y);

    float best = -1.0f;
    int bestp = 0;
    for (int p = threadIdx.x; p < NUM_PRIORS; p += NBLK) {
        const float4 pr = *reinterpret_cast<const float4*>(priors + p * 4);
        const float ltx = fmaxf(pr.x, gb.x);
        const float lty = fmaxf(pr.y, gb.y);
        const float rbx = fminf(pr.z, gb.z);
        const float rby = fminf(pr.w, gb.w);
        const float w = fmaxf(rbx - ltx, 0.0f);
        const float h = fmaxf(rby - lty, 0.0f);
        const float inter = w * h;
        const float area_p = (pr.z - pr.x) * (pr.w - pr.y);
        const float iou = inter / (area_p + area_g - inter);
        if (iou > best) { best = iou; bestp = p; }  // strict > keeps smallest p per thread
    }

    __shared__ float sV[NBLK];
    __shared__ int sI[NBLK];
    sV[threadIdx.x] = best;
    sI[threadIdx.x] = bestp;
    __syncthreads();
    for (int s = NBLK / 2; s > 0; s >>= 1) {
        if (threadIdx.x < s) {
            const float v2 = sV[threadIdx.x + s];
            const int i2 = sI[threadIdx.x + s];
            if (v2 > sV[threadIdx.x] ||
                (v2 == sV[threadIdx.x] && i2 < sI[threadIdx.x])) {
                sV[threadIdx.x] = v2;
                sI[threadIdx.x] = i2;
            }
        }
        __syncthreads();
    }
    if (threadIdx.x == 0) bpi[b * GNUM + g] = sI[0];
}

// ---------------------------------------------------------------------------
// Kernel 2: per (b, p): argmax over g of IoU (first occurrence), apply the
// "every GT keeps its best prior" override (last-g-wins on duplicates, like
// numpy scatter), then SSD-encode and write loc [B,P,4] + conf [B,P].
// ---------------------------------------------------------------------------
__global__ __launch_bounds__(NBLK) void match_kernel(
    const float* __restrict__ priors,    // [P,4]
    const float* __restrict__ gt_boxes,  // [B,G,4]
    const int* __restrict__ gt_labels,   // [B,G]
    const int* __restrict__ bpi,         // [B,G]
    float* __restrict__ out)             // loc [B,P,4] then conf [B,P] (as float)
{
    const int b = blockIdx.y;
    const int p = blockIdx.x * NBLK + threadIdx.x;

    __shared__ float4 sGT[GNUM];
    __shared__ int sLab[GNUM];
    __shared__ int sBpi[GNUM];
    if (threadIdx.x < GNUM) {
        sGT[threadIdx.x] = *reinterpret_cast<const float4*>(
            gt_boxes + (b * GNUM + threadIdx.x) * 4);
        sLab[threadIdx.x] = gt_labels[b * GNUM + threadIdx.x];
        sBpi[threadIdx.x] = bpi[b * GNUM + threadIdx.x];
    }
    __syncthreads();

    const float4 pr = *reinterpret_cast<const float4*>(priors + p * 4);
    const float area_p = (pr.z - pr.x) * (pr.w - pr.y);

    float best = -1.0f;
    int bg = 0;
    int ovr = -1;
    for (int g = 0; g < GNUM; ++g) {
        const float4 gb = sGT[g];
        const float ltx = fmaxf(pr.x, gb.x);
        const float lty = fmaxf(pr.y, gb.y);
        const float rbx = fminf(pr.z, gb.z);
        const float rby = fminf(pr.w, gb.w);
        const float w = fmaxf(rbx - ltx, 0.0f);
        const float h = fmaxf(rby - lty, 0.0f);
        const float inter = w * h;
        const float area_g = (gb.z - gb.x) * (gb.w - gb.y);
        const float iou = inter / (area_p + area_g - inter);
        if (iou > best) { best = iou; bg = g; }   // strict > = first occurrence
        if (sBpi[g] == p) ovr = g;                // ascending g = last-wins
    }

    float best_iou = best;
    int gi = bg;
    if (ovr >= 0) { gi = ovr; best_iou = 2.0f; }

    const float4 m = sGT[gi];
    const int conf = (best_iou < 0.5f) ? 0 : (sLab[gi] + 1);

    // SSD encode: prior center form
    const float pcx = (pr.x + pr.z) * 0.5f;
    const float pcy = (pr.y + pr.w) * 0.5f;
    const float pw = pr.z - pr.x;
    const float ph = pr.w - pr.y;
    const float gcx = (m.x + m.z) * 0.5f;
    const float gcy = (m.y + m.w) * 0.5f;
    const float gw = m.z - m.x;
    const float gh = m.w - m.y;

    float4 loc;
    loc.x = (gcx - pcx) / (0.1f * pw);
    loc.y = (gcy - pcy) / (0.1f * ph);
    loc.z = logf(gw / pw) / 0.2f;
    loc.w = logf(gh / ph) / 0.2f;

    *reinterpret_cast<float4*>(out + ((size_t)b * NUM_PRIORS + p) * 4) = loc;
    out[(size_t)BATCH * NUM_PRIORS * 4 + (size_t)b * NUM_PRIORS + p] = (float)conf;
}

extern "C" void kernel_launch(void* const* d_in, const int* in_sizes, int n_in,
                              void* d_out, int out_size, void* d_ws, size_t ws_size,
                              hipStream_t stream) {
    const float* priors = (const float*)d_in[0];
    const float* gt_boxes = (const float*)d_in[1];
    const int* gt_labels = (const int*)d_in[2];
    float* out = (float*)d_out;
    int* bpi = (int*)d_ws;  // [B*G] ints

    best_prior_kernel<<<BATCH * GNUM, NBLK, 0, stream>>>(priors, gt_boxes, bpi);

    dim3 grid2(NUM_PRIORS / NBLK, BATCH);
    match_kernel<<<grid2, NBLK, 0, stream>>>(priors, gt_boxes, gt_labels, bpi, out);
}

// Round 2
// 114.875 us; speedup vs baseline: 1.4989x; 1.4989x over previous
//
#include <hip/hip_runtime.h>

#define NUM_PRIORS 65536
#define BATCH 8
#define GNUM 64
#define NBLK 256
#define GPB 8      // GTs per block in argmax kernel
#define NCHUNK 32  // prior chunks (65536/32 = 2048 priors per block)
#define PPT 8      // priors per thread = 2048/256

typedef unsigned long long u64;
typedef unsigned int u32;

__device__ inline u64 shfl_down_u64(u64 x, int off) {
    u32 lo = (u32)x, hi = (u32)(x >> 32);
    lo = __shfl_down(lo, off);
    hi = __shfl_down(hi, off);
    return ((u64)hi << 32) | lo;
}

// ---------------------------------------------------------------------------
// Kernel 1: partial per-(b,g) argmax over priors of IoU, combined with
// device-scope atomicMax on packed (iou_bits<<32 | ~p). Ties (equal fp32 iou
// bits) resolve to smallest p == jnp.argmax first-occurrence semantics.
// Grid: (NCHUNK, GNUM/GPB, BATCH), 256 threads.
// ---------------------------------------------------------------------------
__global__ __launch_bounds__(NBLK) void best_prior_partial(
    const float* __restrict__ priors,    // [P,4] corner
    const float* __restrict__ gt_boxes,  // [B,G,4] corner
    u64* __restrict__ bpi_packed)        // [B,G] (zero-initialized)
{
    const int b = blockIdx.z;
    const int g0 = blockIdx.y * GPB;
    const int tid = threadIdx.x;

    __shared__ float4 sGT[GPB];
    __shared__ float sAreaG[GPB];
    if (tid < GPB) {
        const float4 gb = *reinterpret_cast<const float4*>(
            gt_boxes + (b * GNUM + g0 + tid) * 4);
        sGT[tid] = gb;
        sAreaG[tid] = (gb.z - gb.x) * (gb.w - gb.y);
    }
    __syncthreads();

    u64 best[GPB];
#pragma unroll
    for (int g = 0; g < GPB; ++g) best[g] = 0ull;

    const int pbase = blockIdx.x * (NUM_PRIORS / NCHUNK) + tid;
#pragma unroll
    for (int i = 0; i < PPT; ++i) {
        const int p = pbase + i * NBLK;
        const float4 pr = *reinterpret_cast<const float4*>(priors + p * 4);
        const float area_p = (pr.z - pr.x) * (pr.w - pr.y);
        const u32 notp = ~(u32)p;
#pragma unroll
        for (int g = 0; g < GPB; ++g) {
            const float4 gb = sGT[g];
            const float ltx = fmaxf(pr.x, gb.x);
            const float lty = fmaxf(pr.y, gb.y);
            const float rbx = fminf(pr.z, gb.z);
            const float rby = fminf(pr.w, gb.w);
            const float w = fmaxf(rbx - ltx, 0.0f);
            const float h = fmaxf(rby - lty, 0.0f);
            const float inter = w * h;
            const float iou = inter / (area_p + sAreaG[g] - inter);
            const u64 packed = ((u64)__float_as_uint(iou) << 32) | notp;
            best[g] = (packed > best[g]) ? packed : best[g];
        }
    }

    // wave reduce (64 lanes), then cross-wave via LDS, then one atomic per g
    __shared__ u64 sRed[NBLK / 64][GPB];
    const int lane = tid & 63;
    const int wv = tid >> 6;
#pragma unroll
    for (int g = 0; g < GPB; ++g) {
        u64 v = best[g];
#pragma unroll
        for (int off = 32; off > 0; off >>= 1) {
            const u64 o = shfl_down_u64(v, off);
            v = (o > v) ? o : v;
        }
        if (lane == 0) sRed[wv][g] = v;
    }
    __syncthreads();
    if (tid < GPB) {
        u64 v = sRed[0][tid];
#pragma unroll
        for (int w = 1; w < NBLK / 64; ++w) {
            const u64 o = sRed[w][tid];
            v = (o > v) ? o : v;
        }
        atomicMax(&bpi_packed[b * GNUM + g0 + tid], v);
    }
}

// ---------------------------------------------------------------------------
// Kernel 2: per (b, p): argmax over g of IoU (first occurrence), apply the
// "every GT keeps its best prior" override (last-g-wins on duplicates),
// then SSD-encode and write loc [B,P,4] + conf [B,P].
// ---------------------------------------------------------------------------
__global__ __launch_bounds__(NBLK) void match_kernel(
    const float* __restrict__ priors,        // [P,4]
    const float* __restrict__ gt_boxes,      // [B,G,4]
    const int* __restrict__ gt_labels,       // [B,G]
    const u64* __restrict__ bpi_packed,      // [B,G]
    float* __restrict__ out)                 // loc [B,P,4] then conf [B,P]
{
    const int b = blockIdx.y;
    const int p = blockIdx.x * NBLK + threadIdx.x;

    __shared__ float4 sGT[GNUM];
    __shared__ int sLab[GNUM];
    __shared__ int sBpi[GNUM];
    if (threadIdx.x < GNUM) {
        sGT[threadIdx.x] = *reinterpret_cast<const float4*>(
            gt_boxes + (b * GNUM + threadIdx.x) * 4);
        sLab[threadIdx.x] = gt_labels[b * GNUM + threadIdx.x];
        sBpi[threadIdx.x] = (int)(~(u32)(bpi_packed[b * GNUM + threadIdx.x]));
    }
    __syncthreads();

    const float4 pr = *reinterpret_cast<const float4*>(priors + p * 4);
    const float area_p = (pr.z - pr.x) * (pr.w - pr.y);

    float best = -1.0f;
    int bg = 0;
    int ovr = -1;
    for (int g = 0; g < GNUM; ++g) {
        const float4 gb = sGT[g];
        const float ltx = fmaxf(pr.x, gb.x);
        const float lty = fmaxf(pr.y, gb.y);
        const float rbx = fminf(pr.z, gb.z);
        const float rby = fminf(pr.w, gb.w);
        const float w = fmaxf(rbx - ltx, 0.0f);
        const float h = fmaxf(rby - lty, 0.0f);
        const float inter = w * h;
        const float area_g = (gb.z - gb.x) * (gb.w - gb.y);
        const float iou = inter / (area_p + area_g - inter);
        if (iou > best) { best = iou; bg = g; }   // strict > = first occurrence
        if (sBpi[g] == p) ovr = g;                // ascending g = last-wins
    }

    float best_iou = best;
    int gi = bg;
    if (ovr >= 0) { gi = ovr; best_iou = 2.0f; }

    const float4 m = sGT[gi];
    const int conf = (best_iou < 0.5f) ? 0 : (sLab[gi] + 1);

    const float pcx = (pr.x + pr.z) * 0.5f;
    const float pcy = (pr.y + pr.w) * 0.5f;
    const float pw = pr.z - pr.x;
    const float ph = pr.w - pr.y;
    const float gcx = (m.x + m.z) * 0.5f;
    const float gcy = (m.y + m.w) * 0.5f;
    const float gw = m.z - m.x;
    const float gh = m.w - m.y;

    float4 loc;
    loc.x = (gcx - pcx) / (0.1f * pw);
    loc.y = (gcy - pcy) / (0.1f * ph);
    loc.z = logf(gw / pw) / 0.2f;
    loc.w = logf(gh / ph) / 0.2f;

    *reinterpret_cast<float4*>(out + ((size_t)b * NUM_PRIORS + p) * 4) = loc;
    out[(size_t)BATCH * NUM_PRIORS * 4 + (size_t)b * NUM_PRIORS + p] = (float)conf;
}

extern "C" void kernel_launch(void* const* d_in, const int* in_sizes, int n_in,
                              void* d_out, int out_size, void* d_ws, size_t ws_size,
                              hipStream_t stream) {
    const float* priors = (const float*)d_in[0];
    const float* gt_boxes = (const float*)d_in[1];
    const int* gt_labels = (const int*)d_in[2];
    float* out = (float*)d_out;
    u64* bpi_packed = (u64*)d_ws;  // [B*G] packed (iou_bits<<32 | ~p)

    hipMemsetAsync(bpi_packed, 0, BATCH * GNUM * sizeof(u64), stream);

    dim3 grid1(NCHUNK, GNUM / GPB, BATCH);
    best_prior_partial<<<grid1, NBLK, 0, stream>>>(priors, gt_boxes, bpi_packed);

    dim3 grid2(NUM_PRIORS / NBLK, BATCH);
    match_kernel<<<grid2, NBLK, 0, stream>>>(priors, gt_boxes, gt_labels,
                                             bpi_packed, out);
}